// Round 2
// baseline (184.923 us; speedup 1.0000x reference)
//
#include <hip/hip_runtime.h>
#include <hip/hip_bf16.h>
#include <hip/hip_fp8.h>
#include <stdint.h>

#define B_   64
#define L_   512
#define E_   256
#define P_   64
#define KOUT 512
#define KS_  3
#define H_   512
#define T_   53
#define CINW 2688           // conv_w inner: 896*3
#define LE   516            // embp rows/batch: L + 4 (2 zero each side)
#define LPP  514            // posp rows/batch: L + 2 (1 zero each side)
#define COMW 2048           // 1536 ent + 512 sent_h

// fp8 uniform scaling: data x64, weights x64, accumulator /4096
#define FP8_S    64.0f
#define DESCALE  (1.0f / 4096.0f)

// prep-kernel grid sections
#define SEC_CW    0
#define SEC_EMBP  512
#define SEC_POSP  (SEC_EMBP + (B_ * LE / 4))     // 512 + 8256 = 8768
#define SEC_ENT   (SEC_POSP + (B_ * LPP / 4))    // 8768 + 8224 = 16992
#define SEC_POOL  (SEC_ENT + 2 * B_)             // 16992 + 128 = 17120
#define SEC_END   (SEC_POOL + 32)                // 17152

typedef __attribute__((ext_vector_type(4))) float f32x4;
typedef __attribute__((ext_vector_type(4))) int   i32x4;
typedef __attribute__((ext_vector_type(8))) int   i32x8;

__device__ __forceinline__ unsigned enc_f(float x) {
    unsigned u = __float_as_uint(x);
    return (u & 0x80000000u) ? ~u : (u | 0x80000000u);
}
__device__ __forceinline__ float dec_f(unsigned e) {
    return __uint_as_float((e & 0x80000000u) ? (e & 0x7fffffffu) : ~e);
}
__device__ __forceinline__ unsigned char f8c(float x) {
    __hip_fp8_e4m3 t(x);            // OCP e4m3fn (gfx950) — NOT fnuz
    return t.__x;
}

__device__ __forceinline__ void cp16(const void* g, void* l) {
    __builtin_amdgcn_global_load_lds(
        (const __attribute__((address_space(1))) unsigned int*)g,
        (__attribute__((address_space(3))) unsigned int*)l,
        16, 0, 0);
}

// ---------------------------------------------------------------------------
// Fused prep: 5 independent jobs selected by blockIdx.x section.
// CW section now ALSO computes corr[b][which][n] in fp32 (replaces corr_k).
__global__ void prep(const float* __restrict__ conv_w,
                     const int* __restrict__ context,
                     const int* __restrict__ sidx,
                     const int* __restrict__ oidx,
                     const int* __restrict__ sdis,
                     const int* __restrict__ odis,
                     const float* __restrict__ etab,
                     const float* __restrict__ ptab,
                     unsigned char* __restrict__ wce,     // fp8, x64
                     unsigned char* __restrict__ wcp,     // fp8, x64
                     unsigned char* __restrict__ embp,    // fp8, x64
                     unsigned char* __restrict__ posp,    // fp8, x64
                     float* __restrict__ corr,            // fp32 exact
                     float* __restrict__ com,
                     unsigned* __restrict__ pooled) {
    __shared__ float w[CINW];
    const int blk = blockIdx.x;
    const int tid = threadIdx.x;

    if (blk < SEC_EMBP) {
        // ---- combine_w: one block per output channel n ----
        int n = blk;
        const float* src = conv_w + (size_t)n * CINW;
        for (int i = tid; i < CINW; i += 256) w[i] = src[i];
        __syncthreads();
        for (int i = tid; i < 5 * E_; i += 256) {
            int d = i >> 8, c = i & 255;
            float s = 0.f;
#pragma unroll
            for (int tau = 0; tau <= 2; tau++) {
                int seg = d - tau;
                if (seg >= 0 && seg <= 2) s += w[(seg * 256 + c) * 3 + tau];
            }
            wce[((size_t)d * KOUT + n) * E_ + c] = f8c(s * FP8_S);
        }
        for (int i = tid; i < 3 * 128; i += 256) {
            int tau = i >> 7, p = i & 127;
            wcp[((size_t)tau * KOUT + n) * 128 + p] = f8c(w[(768 + p) * 3 + tau] * FP8_S);
        }
        // ---- corr (fp32-exact, replaces corr_k):
        // pair p = (b, which); 2 threads per pair split the 256-dot.
        {
            int p   = tid >> 1, sub = tid & 1;
            int bb  = p >> 1, which = p & 1;
            int token = context[bb * L_ + (which ? L_ - 1 : 0)];
            const float4* er4 = (const float4*)(etab + (size_t)token * E_ + sub * 128);
            // w index: which ? (sub*128+c)*3+2 : (512+sub*128+c)*3+0  == A + 3c
            int A = which ? (sub * 384 + 2) : (1536 + sub * 384);
            float s = 0.f;
#pragma unroll 8
            for (int c4 = 0; c4 < 32; c4++) {
                float4 v = er4[c4];
                int c = c4 * 4;
                s += v.x * w[A + 3 * c]     + v.y * w[A + 3 * c + 3]
                   + v.z * w[A + 3 * c + 6] + v.w * w[A + 3 * c + 9];
            }
            s += __shfl_xor(s, 1, 64);
            if (sub == 0) corr[(bb * 2 + which) * KOUT + n] = s;
        }
    } else if (blk < SEC_POSP) {
        // ---- build_embp (fp8 x64) ----
        int row = (blk - SEC_EMBP) * 4 + (tid >> 6);
        int lane = tid & 63;
        int b = row / LE, r = row % LE;
        unsigned char* out = embp + (size_t)row * E_;
        if (r < 2 || r >= LE - 2) {
            *(uchar4*)(out + lane * 4) = (uchar4){0, 0, 0, 0};
            return;
        }
        int token = context[b * L_ + (r - 2)];
        float4 v = *(const float4*)(etab + (size_t)token * E_ + lane * 4);
        uchar4 pk;
        pk.x = f8c(v.x * FP8_S); pk.y = f8c(v.y * FP8_S);
        pk.z = f8c(v.z * FP8_S); pk.w = f8c(v.w * FP8_S);
        *(uchar4*)(out + lane * 4) = pk;
    } else if (blk < SEC_ENT) {
        // ---- build_posp (fp8 x64) ----
        int row = (blk - SEC_POSP) * 4 + (tid >> 6);
        int lane = tid & 63;
        int b = row / LPP, r = row % LPP;
        unsigned char* out = posp + (size_t)row * 128;
        if (r < 1 || r >= LPP - 1) {
            *(unsigned short*)(out + lane * 2) = 0;
            return;
        }
        int l = r - 1;
        int which = lane >> 5;
        int i2 = (lane & 31) * 2;
        int t = which ? odis[b * L_ + l] : sdis[b * L_ + l];
        float2 v = *(const float2*)(ptab + (size_t)t * P_ + i2);
        unsigned short pk = (unsigned short)f8c(v.x * FP8_S)
                          | ((unsigned short)f8c(v.y * FP8_S) << 8);
        *(unsigned short*)(out + which * 64 + i2) = pk;
    } else if (blk < SEC_POOL) {
        // ---- entity_feats (fp32 exact) ----
        int idx = blk - SEC_ENT;
        int b = idx >> 1, which = idx & 1;
        const int* sp = which ? oidx : sidx;
        int s = sp[b * 2 + 0], e = sp[b * 2 + 1];
        const int* ctx = context + b * L_;
        float* outb = com + (size_t)b * COMW + which * 768;
        int d = tid;
        float sum = 0.f;
        for (int x = s; x <= e; ++x) sum += etab[(size_t)ctx[x] * E_ + d];
        outb[d] = sum / (float)(e - s + 1);
        outb[256 + d] = etab[(size_t)ctx[s - 1] * E_ + d];
        float r = 0.f;
        if (e + 1 < L_) r = etab[(size_t)ctx[e + 1] * E_ + d];
        outb[512 + d] = r;
    } else {
        // ---- zero pooled ----
        int base = ((blk - SEC_POOL) * 256 + tid) * 4;
        *(uint4*)(pooled + base) = (uint4){0, 0, 0, 0};
    }
}

// ---------------------------------------------------------------------------
// R7: A-window staging. The 5 emb taps (and 3 pos taps) are SHIFTED views of
// the same rows, so instead of 13 separate A-tiles (208 KB staged/block) we
// stage one 136-row x 128 B window per kc-phase (3 windows, 49 KB total) and
// read tap t's fragments at window row (tap + wr + i*16 + m). Per-tile staging
// is then B-only (4 cp16/thread, counted vmcnt(4)). LDS 64->49 KB => 3
// blocks/CU for better barrier-stall cover. MX-scaled K=128 fp8 MFMA
// (scales=1.0, numerics == non-scaled fp8) and the verified XOR slot swizzle
// are unchanged from the passing R6 kernel.
__global__ void __launch_bounds__(256, 3)
conv_gemm_pool(const unsigned char* __restrict__ embp,
               const unsigned char* __restrict__ posp,
               const unsigned char* __restrict__ wce,
               const unsigned char* __restrict__ wcp,
               const float* __restrict__ corr,
               unsigned* __restrict__ pooled) {
    __shared__ unsigned char winA[136 * 128];     // 17 KB shared A window
    __shared__ unsigned char sB[2][128 * 128];    // 32 KB B double-buffer

    const int tid  = threadIdx.x;
    const int lane = tid & 63;
    const int wave = tid >> 6;
    const int mt = blockIdx.x;
    const int nt = blockIdx.y;
    const int b  = mt >> 2;
    const int l0 = (mt & 3) * 128;
    const int n0 = nt * 128;

    const int wr = (wave & 1) * 64;
    const int wc = (wave >> 1) * 64;
    const int m  = lane & 15;
    const int q  = lane >> 4;

    f32x4 acc[4][4];
#pragma unroll
    for (int i = 0; i < 4; i++)
#pragma unroll
        for (int j = 0; j < 4; j++) acc[i][j] = (f32x4){0.f, 0.f, 0.f, 0.f};

    // ---- B staging: one 16 KB tile = 4 cp16/thread, linear LDS dest,
    //      pre-swizzled global source (slot ^= row&7 at 16B granularity) ----
    const int srow = tid >> 3;
    const int ssw  = ((tid & 7) ^ (srow & 7)) << 4;
    auto stageB = [&](int buf, int t) {
        const unsigned char* base; int stride;
        if (t < 10) {                       // emb: tiles 0-4 kc=0, 5-9 kc=1
            int tap = (t < 5) ? t : t - 5;
            int kc  = (t < 5) ? 0 : 128;
            base = wce + (size_t)(tap * KOUT + n0) * E_ + kc;
            stride = E_;
        } else {                            // pos: tiles 10-12
            int tap = t - 10;
            base = wcp + (size_t)(tap * KOUT + n0) * 128;
            stride = 128;
        }
        char* dB = (char*)sB[buf] + tid * 16;
#pragma unroll
        for (int rnd = 0; rnd < 4; rnd++)
            cp16(base + (srow + rnd * 32) * stride + ssw, dB + rnd * 4096);
    };

    // ---- A-window staging: 136 rows x 8 chunks (wave-aligned rounds).
    //      Rows beyond the 132/130 needed are staged-but-never-read padding.
    auto stageWin = [&](const unsigned char* base, int stride) {
#pragma unroll
        for (int k = 0; k < 4; k++) {
            int idx = tid + k * 256;
            int r = idx >> 3, c = idx & 7;
            cp16(base + r * stride + ((c ^ (r & 7)) << 4), (char*)winA + idx * 16);
        }
        if (tid < 64) {                     // tail = exactly wave 0
            int idx = tid + 1024;
            int r = idx >> 3, c = idx & 7;
            cp16(base + r * stride + ((c ^ (r & 7)) << 4), (char*)winA + idx * 16);
        }
    };

    // fragment read: lane (m,q) reads logical 16B slots 2q,2q+1 of its row;
    // physical slot = logical ^ (row&7).
    auto frag = [&](const unsigned char* rowbase, int row) -> i32x8 {
        const unsigned char* rp = rowbase + row * 128;
        int x = (row & 7) << 4;
        i32x4 lo = *(const i32x4*)(rp + (((q << 1) << 4) ^ x));
        i32x4 hi = *(const i32x4*)(rp + ((((q << 1) | 1) << 4) ^ x));
        return (i32x8){lo[0], lo[1], lo[2], lo[3], hi[0], hi[1], hi[2], hi[3]};
    };

    auto compute = [&](int buf, int tap) {
        i32x8 af[4];
#pragma unroll
        for (int i = 0; i < 4; i++) af[i] = frag(winA, tap + wr + i * 16 + m);
#pragma unroll
        for (int j = 0; j < 4; j++) {
            i32x8 bfv = frag(sB[buf], wc + j * 16 + m);
#pragma unroll
            for (int i = 0; i < 4; i++)
                // scale bytes 0x7f (e8m0 bias 127) = exactly 1.0
                acc[i][j] = __builtin_amdgcn_mfma_scale_f32_16x16x128_f8f6f4(
                    af[i], bfv, acc[i][j], 0, 0, 0, 0x7f7f7f7f, 0, 0x7f7f7f7f);
        }
    };

    // prologue: emb window kc=0 + first B tile
    stageWin(embp + (size_t)(b * LE + l0) * E_, E_);
    stageB(0, 0);
    asm volatile("s_waitcnt vmcnt(0)" ::: "memory");
    __builtin_amdgcn_s_barrier();

    int cur = 0;
#pragma unroll 1
    for (int t = 0; t < 13; t++) {
        bool pend = (t == 4 || t == 9);      // phase ends (window restage next)
        if (t < 12 && !pend) {
            stageB(cur ^ 1, t + 1);
            asm volatile("s_waitcnt vmcnt(4)" ::: "memory");  // tile t drained
        } else {
            asm volatile("s_waitcnt vmcnt(0)" ::: "memory");
        }
        __builtin_amdgcn_s_barrier();        // tile t ready for all waves
        __builtin_amdgcn_sched_barrier(0);
        compute(cur, (t < 5) ? t : (t < 10 ? t - 5 : t - 10));
        __builtin_amdgcn_sched_barrier(0);
        __builtin_amdgcn_s_barrier();        // tile t consumed by all waves
        if (pend) {
            if (t == 4) stageWin(embp + (size_t)(b * LE + l0) * E_ + 128, E_);
            else        stageWin(posp + (size_t)(b * LPP + l0) * 128, 128);
            stageB(cur ^ 1, t + 1);
            asm volatile("s_waitcnt vmcnt(0)" ::: "memory");
            __builtin_amdgcn_s_barrier();
        }
        cur ^= 1;
    }

    const float* corrb = corr + b * 2 * KOUT;
#pragma unroll
    for (int j = 0; j < 4; j++) {
        int col = n0 + wc + j * 16 + m;
        float mx = -3.4e38f;
#pragma unroll
        for (int i = 0; i < 4; i++)
#pragma unroll
            for (int r = 0; r < 4; r++) {
                float v = acc[i][j][r] * DESCALE;
                int l = l0 + wr + i * 16 + q * 4 + r;
                if (l == 0)      v -= corrb[col];
                if (l == L_ - 1) v -= corrb[KOUT + col];
                mx = fmaxf(mx, v);
            }
        mx = fmaxf(mx, __shfl_xor(mx, 16, 64));
        mx = fmaxf(mx, __shfl_xor(mx, 32, 64));
        if (q == 0) atomicMax(&pooled[b * KOUT + col], enc_f(mx));
    }
}

// ---------------------------------------------------------------------------
__global__ void lin1_k(const unsigned* __restrict__ pooled,
                       const float* __restrict__ conv_b,
                       const float* __restrict__ lin1_w,
                       const float* __restrict__ lin1_b,
                       float* __restrict__ com) {
    int bid = blockIdx.x;
    int wave = threadIdx.x >> 6, lane = threadIdx.x & 63;
    int b = bid >> 7;
    int h = (bid & 127) * 4 + wave;
    const float* w = lin1_w + (size_t)h * KOUT;
    const unsigned* pb = pooled + b * KOUT;
    float s = 0.f;
#pragma unroll
    for (int i = 0; i < 8; i++) {
        int k = lane + 64 * i;
        s += (dec_f(pb[k]) + conv_b[k]) * w[k];
    }
#pragma unroll
    for (int off = 32; off > 0; off >>= 1) s += __shfl_down(s, off, 64);
    if (lane == 0) com[(size_t)b * COMW + 1536 + h] = tanhf(s + lin1_b[h]);
}

__global__ void lin2_k(const float* __restrict__ com,
                       const float* __restrict__ lin2_w,
                       const float* __restrict__ lin2_b,
                       float* __restrict__ out) {
    int b = blockIdx.x;
    int wave = threadIdx.x >> 6, lane = threadIdx.x & 63;
    int t = blockIdx.y * 4 + wave;
    if (t >= T_) return;
    const float* w = lin2_w + (size_t)t * COMW;
    const float* c = com + (size_t)b * COMW;
    float s = 0.f;
#pragma unroll
    for (int i = 0; i < 32; i++) {
        int k = lane + 64 * i;
        s += c[k] * w[k];
    }
#pragma unroll
    for (int off = 32; off > 0; off >>= 1) s += __shfl_down(s, off, 64);
    if (lane == 0) out[b * T_ + t] = s + lin2_b[t];
}

// ---------------------------------------------------------------------------
extern "C" void kernel_launch(void* const* d_in, const int* in_sizes, int n_in,
                              void* d_out, int out_size, void* d_ws, size_t ws_size,
                              hipStream_t stream) {
    const int*   context = (const int*)d_in[0];
    const int*   sidx    = (const int*)d_in[1];
    const int*   oidx    = (const int*)d_in[2];
    const int*   sdis    = (const int*)d_in[3];
    const int*   odis    = (const int*)d_in[4];
    const float* etab    = (const float*)d_in[5];
    const float* ptab    = (const float*)d_in[6];
    const float* conv_w  = (const float*)d_in[7];
    const float* conv_b  = (const float*)d_in[8];
    const float* lin1_w  = (const float*)d_in[9];
    const float* lin1_b  = (const float*)d_in[10];
    const float* lin2_w  = (const float*)d_in[11];
    const float* lin2_b  = (const float*)d_in[12];
    float* out = (float*)d_out;

    char* ws = (char*)d_ws;
    size_t off = 0;
    unsigned char* embp = (unsigned char*)(ws + off);
    off += (size_t)B_ * LE * E_;                 // 8.45 MB (fp8)
    off = (off + 255) & ~(size_t)255;
    unsigned char* posp = (unsigned char*)(ws + off);
    off += (size_t)B_ * LPP * 128;               // 4.2 MB (fp8)
    off = (off + 255) & ~(size_t)255;
    unsigned char* wce = (unsigned char*)(ws + off);
    off += (size_t)5 * KOUT * E_;                // 655 KB (fp8)
    off = (off + 255) & ~(size_t)255;
    unsigned char* wcp = (unsigned char*)(ws + off);
    off += (size_t)3 * KOUT * 128;               // 197 KB (fp8)
    off = (off + 255) & ~(size_t)255;
    float* corr = (float*)(ws + off);
    off += (size_t)B_ * 2 * KOUT * 4;            // 256 KB
    off = (off + 255) & ~(size_t)255;
    unsigned* pooled = (unsigned*)(ws + off);
    off += (size_t)B_ * KOUT * 4;                // 128 KB
    off = (off + 255) & ~(size_t)255;
    float* com = (float*)(ws + off);
    off += (size_t)B_ * COMW * 4;                // 512 KB

    prep<<<dim3(SEC_END), dim3(256), 0, stream>>>(
        conv_w, context, sidx, oidx, sdis, odis, etab, ptab,
        wce, wcp, embp, posp, corr, com, pooled);
    conv_gemm_pool<<<dim3(256, 4), dim3(256), 0, stream>>>(embp, posp, wce, wcp, corr, pooled);
    lin1_k<<<dim3(8192), dim3(256), 0, stream>>>(pooled, conv_b, lin1_w, lin1_b, com);
    lin2_k<<<dim3(B_, 14), dim3(256), 0, stream>>>(com, lin2_w, lin2_b, out);
}